// Round 9
// baseline (812.080 us; speedup 1.0000x reference)
//
#include <hip/hip_runtime.h>

// Sggnn_23218593202512 — round 9: L3-bandwidth attack. R6's gemm_blds h/t ran
// at 494 TF (139us) = ~7.4 TB/s of L3 A-reads (1 GiB/GEMM); u at same 7.3 TB/s
// -> L3-BW-bound. gemm_blds2 doubles cols/block (256x128, 512thr, wave 64x64,
// 4x 64KiB B-stages) -> A L3 traffic halves. Affinity = materialized dg (R6
// pair_kernel) + blds2 with fused scl_W epilogue. Probe: pair_d -> h -> t -> u
// (blds2) -> utrans -> feat (R8 gemm_kernel, verified) -> finout.

typedef __bf16 bf16;
typedef __attribute__((ext_vector_type(8))) __bf16 bf16x8;
typedef __attribute__((ext_vector_type(4))) float f32x4;

#define EPSV 1e-5f

__device__ __forceinline__ void async_load16(const bf16* g, bf16* l) {
    __builtin_amdgcn_global_load_lds(
        (const __attribute__((address_space(1))) void*)g,
        (__attribute__((address_space(3))) void*)l, 16, 0, 0);
}

__global__ __launch_bounds__(256) void prep_kernel(
    const float* __restrict__ g, const float* __restrict__ b,
    const float* __restrict__ m, const float* __restrict__ v,
    const float* __restrict__ bias, float* __restrict__ scale,
    float* __restrict__ offset, int n)
{
    int i = blockIdx.x * 256 + threadIdx.x;
    if (i >= n) return;
    float s = g[i] / sqrtf(v[i] + EPSV);
    float o = b[i] - m[i] * s;
    if (bias) o += bias[i] * s;
    scale[i] = s;
    offset[i] = o;
}

__global__ __launch_bounds__(256) void wtrans_kernel(
    const float* __restrict__ in, bf16* __restrict__ out, int K, int N)
{
    int k = blockIdx.x * 256 + threadIdx.x;
    int n = blockIdx.y;
    out[(size_t)n * K + k] = (bf16)in[(size_t)k * N + n];
}

// D[r][kc..kc+7] = bf16((X[(roff+r)>>8][k]-Y[(roff+r)&255][k])^2*ps[k]+po[k])
__global__ __launch_bounds__(256) void pair_kernel(
    const float* __restrict__ X, const float* __restrict__ Y,
    const float* __restrict__ ps, const float* __restrict__ po,
    bf16* __restrict__ D, int roff)
{
    int gid = blockIdx.x * 256 + threadIdx.x;
    int r = gid >> 7, kc = (gid & 127) * 8;
    int rg = roff + r;
    const float* xp = X + (size_t)(rg >> 8) * 1024 + kc;
    const float* yp = Y + (size_t)(rg & 255) * 1024 + kc;
    f32x4 x0 = *(const f32x4*)xp, x1 = *(const f32x4*)(xp + 4);
    f32x4 y0 = *(const f32x4*)yp, y1 = *(const f32x4*)(yp + 4);
    f32x4 sa = *(const f32x4*)(ps + kc), sb = *(const f32x4*)(ps + kc + 4);
    f32x4 oa = *(const f32x4*)(po + kc), ob = *(const f32x4*)(po + kc + 4);
    bf16x8 dv;
#pragma unroll
    for (int j = 0; j < 4; ++j) {
        float d0 = x0[j] - y0[j], d1 = x1[j] - y1[j];
        dv[j]     = (bf16)(d0 * d0 * sa[j] + oa[j]);
        dv[j + 4] = (bf16)(d1 * d1 * sb[j] + ob[j]);
    }
    *(bf16x8*)(D + (size_t)r * 1024 + kc) = dv;
}

// wT[g2*256+g1] = bf16(w_acc[g1*256+g2] + scl_b)
__global__ __launch_bounds__(256) void wconv_kernel(
    const float* __restrict__ w_acc, const float* __restrict__ sclb,
    bf16* __restrict__ wT)
{
    int tid = blockIdx.x * 256 + threadIdx.x;
    int g2 = tid >> 8, g1 = tid & 255;
    wT[tid] = (bf16)(w_acc[g1 * 256 + g2] + sclb[0]);
}

__global__ __launch_bounds__(256) void utrans_kernel(
    const bf16* __restrict__ u, bf16* __restrict__ uT)
{
    __shared__ float tile[64][65];
    int g0 = blockIdx.x * 64, h0 = blockIdx.y * 64, p = blockIdx.z;
    const bf16* up = u + (size_t)p * 256 * 512;
    bf16* op = uT + (size_t)p * 512 * 256;
    for (int c = threadIdx.x; c < 512; c += 256) {
        int r = c >> 3, hc = (c & 7) * 8;
        bf16x8 val = *(const bf16x8*)(up + (size_t)(g0 + r) * 512 + h0 + hc);
#pragma unroll
        for (int j = 0; j < 8; ++j) tile[r][hc + j] = (float)val[j];
    }
    __syncthreads();
    for (int c = threadIdx.x; c < 512; c += 256) {
        int hr = c >> 3, gc = (c & 7) * 8;
        bf16x8 val;
#pragma unroll
        for (int j = 0; j < 8; ++j) val[j] = (bf16)tile[gc + j][hr];
        *(bf16x8*)(op + (size_t)(h0 + hr) * 256 + g0 + gc) = val;
    }
}

__global__ __launch_bounds__(256) void finout_kernel(
    const float* __restrict__ acc, const float* __restrict__ clsb,
    float* __restrict__ out)
{
    int i = blockIdx.x * 256 + threadIdx.x;
    out[i] = acc[i] + clsb[0];
}

// ---------- blds2: C[M,N] = epi(A[M,1024] @ BT[N,1024]^T) -----------------
// Block 256 rows x 128 cols, 512 thr = 8 waves (4 row x 2 col), wave 64x64
// (acc[4][4]). B staged in 4 stages of 128 cols x 256 K (64 KiB LDS,
// XOR-swizzled 16B chunks over 32 chunks/row). A streamed as direct global
// bf16x8 frag loads (L1/L2/L3-served; 256-row blocks halve L3 traffic vs R6).
// XCD-grouped decode. fuseW: rs += lrelu(bn(val))*fuseW[col] -> atomicAdd.
__global__ __launch_bounds__(512) void gemm_blds2(
    const bf16* __restrict__ A, const bf16* __restrict__ BT,
    bf16* __restrict__ C, int N, int nColB, int nRowBdiv8,
    const float* __restrict__ scale, const float* __restrict__ offset,
    int lrelu, const float* __restrict__ fuseW, float* __restrict__ facc)
{
    __shared__ bf16 Bs[128 * 256];   // 64 KiB
    const int tid  = threadIdx.x;
    const int lane = tid & 63;
    const int wave = tid >> 6;
    const int wrow = wave >> 1, wcol = wave & 1;
    const int q = lane >> 4, l16 = lane & 15;

    int b = blockIdx.x;
    int xcd = b & 7, j = b >> 3;
    int colb = j % nColB, rl = j / nColB;
    int rowb = xcd * nRowBdiv8 + rl;
    const int row0 = rowb * 256, col0 = colb * 128;

    f32x4 acc[4][4];
#pragma unroll
    for (int mi = 0; mi < 4; ++mi)
#pragma unroll
        for (int ni = 0; ni < 4; ++ni)
#pragma unroll
            for (int e = 0; e < 4; ++e) acc[mi][ni][e] = 0.f;

    const bf16* Arow[4];
#pragma unroll
    for (int mi = 0; mi < 4; ++mi)
        Arow[mi] = A + (size_t)(row0 + wrow * 64 + mi * 16 + l16) * 1024 + q * 8;

    for (int ks = 0; ks < 4; ++ks) {
        const int koff = ks * 256;
        // stage B panel: 128 cols x 256 K = 4096 16B-chunks, 8 per thread
#pragma unroll
        for (int i = 0; i < 8; ++i) {
            int idx = i * 512 + tid;
            int c = idx >> 5, sch = idx & 31;
            int gch = sch ^ (c & 31);
            async_load16(BT + (size_t)(col0 + c) * 1024 + koff + gch * 8,
                         &Bs[idx * 8]);
        }
        __syncthreads();

#pragma unroll
        for (int it = 0; it < 8; ++it) {
            bf16x8 af[4], bfr[4];
            const int klocal = it * 32;
#pragma unroll
            for (int mi = 0; mi < 4; ++mi)
                af[mi] = *(const bf16x8*)(Arow[mi] + koff + klocal);
#pragma unroll
            for (int ni = 0; ni < 4; ++ni) {
                int c = wcol * 64 + ni * 16 + l16;
                int sch = (it * 4 + q) ^ (c & 31);
                bfr[ni] = *(const bf16x8*)&Bs[c * 256 + sch * 8];
            }
#pragma unroll
            for (int mi = 0; mi < 4; ++mi)
#pragma unroll
                for (int ni = 0; ni < 4; ++ni)
                    acc[mi][ni] = __builtin_amdgcn_mfma_f32_16x16x32_bf16(
                        af[mi], bfr[ni], acc[mi][ni], 0, 0, 0);
        }
        __syncthreads();
    }

    // C/D layout (m89-verified): col = lane&15, row = (lane>>4)*4 + reg
    if (fuseW) {
#pragma unroll
        for (int mi = 0; mi < 4; ++mi)
#pragma unroll
            for (int i = 0; i < 4; ++i) {
                float rs = 0.f;
#pragma unroll
                for (int ni = 0; ni < 4; ++ni) {
                    int cc = col0 + wcol * 64 + ni * 16 + l16;
                    float val = acc[mi][ni][i] * scale[cc] + offset[cc];
                    val = val > 0.f ? val : 0.1f * val;
                    rs += val * fuseW[cc];
                }
                rs += __shfl_xor(rs, 1, 64);
                rs += __shfl_xor(rs, 2, 64);
                rs += __shfl_xor(rs, 4, 64);
                rs += __shfl_xor(rs, 8, 64);
                if (l16 == 0) {
                    int r = row0 + wrow * 64 + mi * 16 + q * 4 + i;
                    atomicAdd(facc + r, rs);
                }
            }
        return;
    }
#pragma unroll
    for (int mi = 0; mi < 4; ++mi)
#pragma unroll
        for (int ni = 0; ni < 4; ++ni)
#pragma unroll
            for (int i = 0; i < 4; ++i) {
                int r = row0 + wrow * 64 + mi * 16 + q * 4 + i;
                int cc = col0 + wcol * 64 + ni * 16 + l16;
                float val = acc[mi][ni][i];
                if (scale) val = val * scale[cc] + offset[cc];
                if (lrelu) val = val > 0.f ? val : 0.1f * val;
                C[(size_t)r * N + cc] = (bf16)val;
            }
}

// ---------- R8 gemm (verified) for the batched featfused stage -------------
__global__ __launch_bounds__(256) void gemm_kernel(
    const bf16* __restrict__ A,
    const bf16* __restrict__ BT, bf16* __restrict__ C,
    int K, int N, long long batchB, long long batchC,
    const float* __restrict__ scale, const float* __restrict__ offset,
    int lrelu, const float* __restrict__ fuseW, float* __restrict__ facc,
    long long faccStride)
{
    __shared__ bf16 As[128 * 64];
    __shared__ bf16 Bs[128 * 64];
    const int tid  = threadIdx.x;
    const int lane = tid & 63;
    const int wave = tid >> 6;
    const int wr = wave >> 1, wc = wave & 1;
    const int row0 = blockIdx.y * 128;
    const int col0 = blockIdx.x * 128;
    const int q = lane >> 4, l16 = lane & 15;
    const int drow = lane >> 3;
    const int dsch = lane & 7;

    const bf16* Bp = BT + (size_t)blockIdx.z * (size_t)batchB;
    bf16* Cp = C + (size_t)blockIdx.z * (size_t)batchC;

    f32x4 acc[4][4];
#pragma unroll
    for (int mi = 0; mi < 4; ++mi)
#pragma unroll
        for (int ni = 0; ni < 4; ++ni)
#pragma unroll
            for (int e = 0; e < 4; ++e) acc[mi][ni][e] = 0.f;

    for (int kk = 0; kk < K; kk += 64) {
#pragma unroll
        for (int t = 0; t < 4; ++t) {
            int grp = wave * 4 + t;
            int r = grp * 8 + drow;
            int gch = dsch ^ (r & 7);
            async_load16(A + (size_t)(row0 + r) * K + kk + gch * 8,
                         &As[grp * 512 + lane * 8]);
        }
#pragma unroll
        for (int t = 0; t < 4; ++t) {
            int grp = wave * 4 + t;
            int r = grp * 8 + drow;
            int gch = dsch ^ (r & 7);
            async_load16(Bp + (size_t)(col0 + r) * K + kk + gch * 8,
                         &Bs[grp * 512 + lane * 8]);
        }
        __syncthreads();
#pragma unroll
        for (int s = 0; s < 2; ++s) {
            bf16x8 af[4], bfr[4];
#pragma unroll
            for (int mi = 0; mi < 4; ++mi) {
                int r = wr * 64 + mi * 16 + l16;
                af[mi] = *(const bf16x8*)&As[r * 64 + (((s * 4 + q) ^ (r & 7)) * 8)];
            }
#pragma unroll
            for (int ni = 0; ni < 4; ++ni) {
                int rc = wc * 64 + ni * 16 + l16;
                bfr[ni] = *(const bf16x8*)&Bs[rc * 64 + (((s * 4 + q) ^ (rc & 7)) * 8)];
            }
#pragma unroll
            for (int mi = 0; mi < 4; ++mi)
#pragma unroll
                for (int ni = 0; ni < 4; ++ni)
                    acc[mi][ni] = __builtin_amdgcn_mfma_f32_16x16x32_bf16(
                        af[mi], bfr[ni], acc[mi][ni], 0, 0, 0);
        }
        __syncthreads();
    }

    if (fuseW) {
#pragma unroll
        for (int mi = 0; mi < 4; ++mi)
#pragma unroll
            for (int i = 0; i < 4; ++i) {
                float rs = 0.f;
#pragma unroll
                for (int ni = 0; ni < 4; ++ni) {
                    int cc = col0 + wc * 64 + ni * 16 + l16;
                    float val = acc[mi][ni][i] * scale[cc] + offset[cc];
                    val = val > 0.f ? val : 0.1f * val;
                    rs += val * fuseW[cc];
                }
                rs += __shfl_xor(rs, 1, 64);
                rs += __shfl_xor(rs, 2, 64);
                rs += __shfl_xor(rs, 4, 64);
                rs += __shfl_xor(rs, 8, 64);
                if (l16 == 0) {
                    int r = row0 + wr * 64 + mi * 16 + q * 4 + i;
                    atomicAdd(facc + (size_t)blockIdx.z * faccStride + r, rs);
                }
            }
        return;
    }
#pragma unroll
    for (int mi = 0; mi < 4; ++mi)
#pragma unroll
        for (int ni = 0; ni < 4; ++ni)
#pragma unroll
            for (int i = 0; i < 4; ++i) {
                int r = row0 + wr * 64 + mi * 16 + q * 4 + i;
                int cc = col0 + wc * 64 + ni * 16 + l16;
                float val = acc[mi][ni][i];
                if (scale) val = val * scale[cc] + offset[cc];
                if (lrelu) val = val > 0.f ? val : 0.1f * val;
                Cp[(size_t)r * N + cc] = (bf16)val;
            }
}

extern "C" void kernel_launch(void* const* d_in, const int* in_sizes, int n_in,
                              void* d_out, int out_size, void* d_ws, size_t ws_size,
                              hipStream_t stream)
{
    const float* f_p   = (const float*)d_in[0];
    const float* f_g   = (const float*)d_in[1];
    const float* bn_g  = (const float*)d_in[2];
    const float* bn_b  = (const float*)d_in[3];
    const float* bn_m  = (const float*)d_in[4];
    const float* bn_v  = (const float*)d_in[5];
    const float* rf_W1 = (const float*)d_in[6];
    const float* rf_b1 = (const float*)d_in[7];
    const float* rf1_g = (const float*)d_in[8];
    const float* rf1_b = (const float*)d_in[9];
    const float* rf1_m = (const float*)d_in[10];
    const float* rf1_v = (const float*)d_in[11];
    const float* rf_W2 = (const float*)d_in[12];
    const float* rf_b2 = (const float*)d_in[13];
    const float* rf2_g = (const float*)d_in[14];
    const float* rf2_b = (const float*)d_in[15];
    const float* rf2_m = (const float*)d_in[16];
    const float* rf2_v = (const float*)d_in[17];
    const float* sfc_W = (const float*)d_in[18];
    const float* sfc_b = (const float*)d_in[19];
    const float* sbn_g = (const float*)d_in[20];
    const float* sbn_b = (const float*)d_in[21];
    const float* sbn_m = (const float*)d_in[22];
    const float* sbn_v = (const float*)d_in[23];
    const float* scl_W = (const float*)d_in[24];
    const float* scl_b = (const float*)d_in[25];
    const float* ffc_W = (const float*)d_in[26];
    const float* ffc_b = (const float*)d_in[27];
    const float* fbn_g = (const float*)d_in[28];
    const float* fbn_b = (const float*)d_in[29];
    const float* fbn_m = (const float*)d_in[30];
    const float* fbn_v = (const float*)d_in[31];
    const float* cls_W = (const float*)d_in[32];
    const float* cls_b = (const float*)d_in[33];

    const size_t MB = 1ull << 20;
    char* ws = (char*)d_ws;
    float* SC      = (float*)(ws);
    float *s0 = SC,        *o0 = SC + 1024;
    float *s1 = SC + 2048, *o1 = SC + 3072;
    float *s2 = SC + 4096, *o2 = SC + 5120;
    float *s3 = SC + 6144, *o3 = SC + 6656;
    float *s4 = SC + 7168, *o4 = SC + 7680;
    float* w_acc   = (float*)(ws + 65536);       // 256 KiB
    float* out_acc = (float*)(ws + 327680);      // 128 KiB
    bf16* wT       = (bf16*)(ws + 458752);       // 128 KiB
    bf16* W1T      = (bf16*)(ws + 1 * MB);
    bf16* W2T      = (bf16*)(ws + 3 * MB);
    bf16* sfcT     = (bf16*)(ws + 5 * MB);
    bf16* ffcT     = (bf16*)(ws + 6 * MB);

    // affinity dg: full (128 MiB) if ws >= 140 MB (ws>=170 confirmed R3-R8)
    const int naff = (ws_size >= 140 * MB) ? 1 : 2;
    // probe chain: nc=1 needs d+h+t resident = 8+192=200 MiB
    const int nc = (ws_size >= 204 * MB) ? 1 : 2;
    const int pc = 128 / nc;
    const int R  = pc * 256;
    const size_t csz = (size_t)R * 1024 * 2;     // d/h/t chunk bytes
    bf16* dgbuf = (bf16*)(ws + 8 * MB);          // affinity dg (dead after)
    bf16* dbuf  = (bf16*)(ws + 8 * MB);
    bf16* hbuf  = (bf16*)(ws + 8 * MB + csz);
    bf16* tbuf  = (bf16*)(ws + 8 * MB + 2 * csz);
    bf16* ubuf  = (bf16*)(ws + 8 * MB);                  // reuses d (dead)
    bf16* uTbuf = (bf16*)(ws + 8 * MB + csz / 2);        // after u

    // 1. BN folds
    prep_kernel<<<dim3(4), 256, 0, stream>>>(bn_g, bn_b, bn_m, bn_v, nullptr, s0, o0, 1024);
    prep_kernel<<<dim3(4), 256, 0, stream>>>(rf1_g, rf1_b, rf1_m, rf1_v, rf_b1, s1, o1, 1024);
    prep_kernel<<<dim3(4), 256, 0, stream>>>(rf2_g, rf2_b, rf2_m, rf2_v, rf_b2, s2, o2, 1024);
    prep_kernel<<<dim3(2), 256, 0, stream>>>(sbn_g, sbn_b, sbn_m, sbn_v, sfc_b, s3, o3, 512);
    prep_kernel<<<dim3(2), 256, 0, stream>>>(fbn_g, fbn_b, fbn_m, fbn_v, ffc_b, s4, o4, 512);

    // 2. weight transposes (f32 -> bf16)
    wtrans_kernel<<<dim3(4, 1024), 256, 0, stream>>>(rf_W1, W1T, 1024, 1024);
    wtrans_kernel<<<dim3(4, 1024), 256, 0, stream>>>(rf_W2, W2T, 1024, 1024);
    wtrans_kernel<<<dim3(4, 512), 256, 0, stream>>>(sfc_W, sfcT, 1024, 512);
    wtrans_kernel<<<dim3(4, 512), 256, 0, stream>>>(ffc_W, ffcT, 1024, 512);

    // 3. zero accumulators
    hipMemsetAsync(ws + 65536, 0, 393216, stream);

    // 4. affinity: dg materialized, blds2 with fused scl_W -> w_acc
    for (int ai = 0; ai < naff; ++ai) {
        const int arows = 65536 / naff;
        pair_kernel<<<dim3(arows / 2), 256, 0, stream>>>(
            f_g, f_g, s0, o0, dgbuf, ai * arows);
        gemm_blds2<<<dim3((arows / 256) * 4), 512, 0, stream>>>(
            dgbuf, sfcT, nullptr, 512, 4, arows / 2048,
            s3, o3, 1, scl_W, w_acc + ai * arows);
    }
    // 5. wT[g2][g1] = bf16(w[g1][g2] + scl_b)
    wconv_kernel<<<dim3(256), 256, 0, stream>>>(w_acc, scl_b, wT);

    // 6. probe chunks
    for (int ci = 0; ci < nc; ++ci) {
        pair_kernel<<<dim3(R / 2), 256, 0, stream>>>(
            f_p, f_g, s0, o0, dbuf, ci * R);
        // h = lrelu(rf1(d @ W1 + b1))   [R,1024]
        gemm_blds2<<<dim3((R / 256) * 8), 512, 0, stream>>>(
            dbuf, W1T, hbuf, 1024, 8, R / 2048, s1, o1, 1, nullptr, nullptr);
        // t = lrelu(rf2(h @ W2 + b2))   [R,1024]
        gemm_blds2<<<dim3((R / 256) * 8), 512, 0, stream>>>(
            hbuf, W2T, tbuf, 1024, 8, R / 2048, s2, o2, 1, nullptr, nullptr);
        // u = t @ ffc_W                 [R,512]  (d dead -> ubuf @ base)
        gemm_blds2<<<dim3((R / 256) * 4), 512, 0, stream>>>(
            tbuf, ffcT, ubuf, 512, 4, R / 2048, nullptr, nullptr, 0, nullptr, nullptr);
        // uT[p][h][g]
        utrans_kernel<<<dim3(4, 8, pc), 256, 0, stream>>>(ubuf, uTbuf);
        // fused feat+classifier -> out_acc
        gemm_kernel<<<dim3(4, 2, pc), 256, 0, stream>>>(
            wT, uTbuf, nullptr, 256, 512, (long long)512 * 256, 0,
            s4, o4, 1, cls_W, out_acc + (size_t)ci * pc * 256, 256);
    }
    // 7. d_out = out_acc + cls_b
    finout_kernel<<<dim3(128), 256, 0, stream>>>(out_acc, cls_b, (float*)d_out);
}

// Round 10
// 601.666 us; speedup vs baseline: 1.3497x; 1.3497x over previous
//
#include <hip/hip_runtime.h>

// Sggnn_23218593202512 — round 10: FLOP-per-staged-byte attack. All prior
// structures converge to ~350-380 TF at ~5.3 TB/s of operand staging;
// gemm256 (256x256 block, 512thr, wave 128x64, BK=64) doubles FLOP/staged-byte
// (64 -> 128 FLOP/B) with identical per-iter structure to R8 (verified).
// Pair construction fused back into staging (dg/d never materialized).
// feat stage keeps R9's verified batched gemm_kernel.

typedef __bf16 bf16;
typedef __attribute__((ext_vector_type(8))) __bf16 bf16x8;
typedef __attribute__((ext_vector_type(4))) float f32x4;

#define EPSV 1e-5f

__device__ __forceinline__ void async_load16(const bf16* g, bf16* l) {
    __builtin_amdgcn_global_load_lds(
        (const __attribute__((address_space(1))) void*)g,
        (__attribute__((address_space(3))) void*)l, 16, 0, 0);
}

__global__ __launch_bounds__(256) void prep_kernel(
    const float* __restrict__ g, const float* __restrict__ b,
    const float* __restrict__ m, const float* __restrict__ v,
    const float* __restrict__ bias, float* __restrict__ scale,
    float* __restrict__ offset, int n)
{
    int i = blockIdx.x * 256 + threadIdx.x;
    if (i >= n) return;
    float s = g[i] / sqrtf(v[i] + EPSV);
    float o = b[i] - m[i] * s;
    if (bias) o += bias[i] * s;
    scale[i] = s;
    offset[i] = o;
}

__global__ __launch_bounds__(256) void wtrans_kernel(
    const float* __restrict__ in, bf16* __restrict__ out, int K, int N)
{
    int k = blockIdx.x * 256 + threadIdx.x;
    int n = blockIdx.y;
    out[(size_t)n * K + k] = (bf16)in[(size_t)k * N + n];
}

// wT[g2*256+g1] = bf16(w_acc[g1*256+g2] + scl_b)
__global__ __launch_bounds__(256) void wconv_kernel(
    const float* __restrict__ w_acc, const float* __restrict__ sclb,
    bf16* __restrict__ wT)
{
    int tid = blockIdx.x * 256 + threadIdx.x;
    int g2 = tid >> 8, g1 = tid & 255;
    wT[tid] = (bf16)(w_acc[g1 * 256 + g2] + sclb[0]);
}

__global__ __launch_bounds__(256) void utrans_kernel(
    const bf16* __restrict__ u, bf16* __restrict__ uT)
{
    __shared__ float tile[64][65];
    int g0 = blockIdx.x * 64, h0 = blockIdx.y * 64, p = blockIdx.z;
    const bf16* up = u + (size_t)p * 256 * 512;
    bf16* op = uT + (size_t)p * 512 * 256;
    for (int c = threadIdx.x; c < 512; c += 256) {
        int r = c >> 3, hc = (c & 7) * 8;
        bf16x8 val = *(const bf16x8*)(up + (size_t)(g0 + r) * 512 + h0 + hc);
#pragma unroll
        for (int j = 0; j < 8; ++j) tile[r][hc + j] = (float)val[j];
    }
    __syncthreads();
    for (int c = threadIdx.x; c < 512; c += 256) {
        int hr = c >> 3, gc = (c & 7) * 8;
        bf16x8 val;
#pragma unroll
        for (int j = 0; j < 8; ++j) val[j] = (bf16)tile[gc + j][hr];
        *(bf16x8*)(op + (size_t)(h0 + hr) * 256 + g0 + gc) = val;
    }
}

__global__ __launch_bounds__(256) void finout_kernel(
    const float* __restrict__ acc, const float* __restrict__ clsb,
    float* __restrict__ out)
{
    int i = blockIdx.x * 256 + threadIdx.x;
    out[i] = acc[i] + clsb[0];
}

// ---------- gemm256: C[M,N] = epi(A[M,K] @ BT[N,K]^T) ----------------------
// 256x256 block tile, 512 thr = 8 waves (2 row x 4 col), wave 128x64
// (acc[8][4]). BK=64, As/Bs 32 KiB each, XOR-swizzled 16B chunks
// (store chunk = global chunk ^ (row&7)); same verified scheme as R8.
// pair mode (pairX!=0, f32): A[r][k]=(X[gr>>8][k]-Y[gr&255][k])^2*ps[k]+po[k],
//   gr = rowOff + row0 + r.
// fuseW: rs += lrelu(bn(val))*fuseW[col] -> atomicAdd facc[row0+...]
__global__ __launch_bounds__(512) void gemm256(
    const bf16* __restrict__ A,
    const float* __restrict__ pairX, const float* __restrict__ pairY,
    const float* __restrict__ ps, const float* __restrict__ po,
    const bf16* __restrict__ BT,
    bf16* __restrict__ C,
    int K, int N, int rowOff,
    const float* __restrict__ scale, const float* __restrict__ offset,
    int lrelu,
    const float* __restrict__ fuseW, float* __restrict__ facc)
{
    __shared__ bf16 As[256 * 64];   // 32 KiB
    __shared__ bf16 Bs[256 * 64];   // 32 KiB
    const int tid  = threadIdx.x;
    const int lane = tid & 63;
    const int wave = tid >> 6;
    const int wrow = wave >> 2, wcol = wave & 3;
    const int row0 = blockIdx.y * 256;
    const int col0 = blockIdx.x * 256;   // 256-col block; wave covers 64
    const int q = lane >> 4, l16 = lane & 15;

    f32x4 acc[8][4];
#pragma unroll
    for (int mi = 0; mi < 8; ++mi)
#pragma unroll
        for (int ni = 0; ni < 4; ++ni)
#pragma unroll
            for (int e = 0; e < 4; ++e) acc[mi][ni][e] = 0.f;

    for (int kk = 0; kk < K; kk += 64) {
        if (pairX) {
#pragma unroll
            for (int t = 0; t < 4; ++t) {
                int c = tid + t * 512;      // 2048 tasks: r=c>>3, chunk=c&7
                int r = c >> 3, ch = c & 7;
                int gr = rowOff + row0 + r;
                const float* xp = pairX + (size_t)(gr >> 8) * K + kk + ch * 8;
                const float* yp = pairY + (size_t)(gr & 255) * K + kk + ch * 8;
                f32x4 x0 = *(const f32x4*)xp, x1 = *(const f32x4*)(xp + 4);
                f32x4 y0 = *(const f32x4*)yp, y1 = *(const f32x4*)(yp + 4);
                f32x4 sa = *(const f32x4*)(ps + kk + ch * 8);
                f32x4 sb = *(const f32x4*)(ps + kk + ch * 8 + 4);
                f32x4 oa = *(const f32x4*)(po + kk + ch * 8);
                f32x4 ob = *(const f32x4*)(po + kk + ch * 8 + 4);
                bf16x8 dv;
#pragma unroll
                for (int j = 0; j < 4; ++j) {
                    float d0 = x0[j] - y0[j];
                    float d1 = x1[j] - y1[j];
                    dv[j]     = (bf16)(d0 * d0 * sa[j] + oa[j]);
                    dv[j + 4] = (bf16)(d1 * d1 * sb[j] + ob[j]);
                }
                *(bf16x8*)&As[r * 64 + ((ch ^ (r & 7)) * 8)] = dv;
            }
        } else {
#pragma unroll
            for (int t = 0; t < 4; ++t) {
                int idx = t * 512 + tid;    // 2048 chunks; dest lane*16 contig
                int r = idx >> 3, sch = idx & 7;
                int gch = sch ^ (r & 7);
                async_load16(A + (size_t)(row0 + r) * K + kk + gch * 8,
                             &As[idx * 8]);
            }
        }
#pragma unroll
        for (int t = 0; t < 4; ++t) {
            int idx = t * 512 + tid;
            int r = idx >> 3, sch = idx & 7;
            int gch = sch ^ (r & 7);
            async_load16(BT + (size_t)(col0 + r) * K + kk + gch * 8,
                         &Bs[idx * 8]);
        }
        __syncthreads();

#pragma unroll
        for (int s = 0; s < 2; ++s) {       // two k-steps of 32
            bf16x8 af[8], bfr[4];
#pragma unroll
            for (int mi = 0; mi < 8; ++mi) {
                int r = wrow * 128 + mi * 16 + l16;
                af[mi] = *(const bf16x8*)&As[r * 64 + (((s * 4 + q) ^ (r & 7)) * 8)];
            }
#pragma unroll
            for (int ni = 0; ni < 4; ++ni) {
                int rc = wcol * 64 + ni * 16 + l16;
                bfr[ni] = *(const bf16x8*)&Bs[rc * 64 + (((s * 4 + q) ^ (rc & 7)) * 8)];
            }
#pragma unroll
            for (int mi = 0; mi < 8; ++mi)
#pragma unroll
                for (int ni = 0; ni < 4; ++ni)
                    acc[mi][ni] = __builtin_amdgcn_mfma_f32_16x16x32_bf16(
                        af[mi], bfr[ni], acc[mi][ni], 0, 0, 0);
        }
        __syncthreads();
    }

    // C/D layout (m89-verified): col = lane&15, row = (lane>>4)*4 + reg
    if (fuseW) {
#pragma unroll
        for (int mi = 0; mi < 8; ++mi)
#pragma unroll
            for (int i = 0; i < 4; ++i) {
                float rs = 0.f;
#pragma unroll
                for (int ni = 0; ni < 4; ++ni) {
                    int cc = col0 + wcol * 64 + ni * 16 + l16;
                    float val = acc[mi][ni][i] * scale[cc] + offset[cc];
                    val = val > 0.f ? val : 0.1f * val;
                    rs += val * fuseW[cc];
                }
                rs += __shfl_xor(rs, 1, 64);
                rs += __shfl_xor(rs, 2, 64);
                rs += __shfl_xor(rs, 4, 64);
                rs += __shfl_xor(rs, 8, 64);
                if (l16 == 0) {
                    int r = row0 + wrow * 128 + mi * 16 + q * 4 + i;
                    atomicAdd(facc + r, rs);
                }
            }
        return;
    }
#pragma unroll
    for (int mi = 0; mi < 8; ++mi)
#pragma unroll
        for (int ni = 0; ni < 4; ++ni)
#pragma unroll
            for (int i = 0; i < 4; ++i) {
                int r = row0 + wrow * 128 + mi * 16 + q * 4 + i;
                int cc = col0 + wcol * 64 + ni * 16 + l16;
                float val = acc[mi][ni][i];
                if (scale) val = val * scale[cc] + offset[cc];
                if (lrelu) val = val > 0.f ? val : 0.1f * val;
                C[(size_t)r * N + cc] = (bf16)val;
            }
}

// ---------- R9-verified gemm (batched) for the feat+classifier stage -------
__global__ __launch_bounds__(256) void gemm_kernel(
    const bf16* __restrict__ A,
    const bf16* __restrict__ BT, bf16* __restrict__ C,
    int K, int N, long long batchB, long long batchC,
    const float* __restrict__ scale, const float* __restrict__ offset,
    int lrelu, const float* __restrict__ fuseW, float* __restrict__ facc,
    long long faccStride)
{
    __shared__ bf16 As[128 * 64];
    __shared__ bf16 Bs[128 * 64];
    const int tid  = threadIdx.x;
    const int lane = tid & 63;
    const int wave = tid >> 6;
    const int wr = wave >> 1, wc = wave & 1;
    const int row0 = blockIdx.y * 128;
    const int col0 = blockIdx.x * 128;
    const int q = lane >> 4, l16 = lane & 15;
    const int drow = lane >> 3;
    const int dsch = lane & 7;

    const bf16* Bp = BT + (size_t)blockIdx.z * (size_t)batchB;
    bf16* Cp = C + (size_t)blockIdx.z * (size_t)batchC;

    f32x4 acc[4][4];
#pragma unroll
    for (int mi = 0; mi < 4; ++mi)
#pragma unroll
        for (int ni = 0; ni < 4; ++ni)
#pragma unroll
            for (int e = 0; e < 4; ++e) acc[mi][ni][e] = 0.f;

    for (int kk = 0; kk < K; kk += 64) {
#pragma unroll
        for (int t = 0; t < 4; ++t) {
            int grp = wave * 4 + t;
            int r = grp * 8 + drow;
            int gch = dsch ^ (r & 7);
            async_load16(A + (size_t)(row0 + r) * K + kk + gch * 8,
                         &As[grp * 512 + lane * 8]);
        }
#pragma unroll
        for (int t = 0; t < 4; ++t) {
            int grp = wave * 4 + t;
            int r = grp * 8 + drow;
            int gch = dsch ^ (r & 7);
            async_load16(Bp + (size_t)(col0 + r) * K + kk + gch * 8,
                         &Bs[grp * 512 + lane * 8]);
        }
        __syncthreads();
#pragma unroll
        for (int s = 0; s < 2; ++s) {
            bf16x8 af[4], bfr[4];
#pragma unroll
            for (int mi = 0; mi < 4; ++mi) {
                int r = wr * 64 + mi * 16 + l16;
                af[mi] = *(const bf16x8*)&As[r * 64 + (((s * 4 + q) ^ (r & 7)) * 8)];
            }
#pragma unroll
            for (int ni = 0; ni < 4; ++ni) {
                int rc = wc * 64 + ni * 16 + l16;
                bfr[ni] = *(const bf16x8*)&Bs[rc * 64 + (((s * 4 + q) ^ (rc & 7)) * 8)];
            }
#pragma unroll
            for (int mi = 0; mi < 4; ++mi)
#pragma unroll
                for (int ni = 0; ni < 4; ++ni)
                    acc[mi][ni] = __builtin_amdgcn_mfma_f32_16x16x32_bf16(
                        af[mi], bfr[ni], acc[mi][ni], 0, 0, 0);
        }
        __syncthreads();
    }

    if (fuseW) {
#pragma unroll
        for (int mi = 0; mi < 4; ++mi)
#pragma unroll
            for (int i = 0; i < 4; ++i) {
                float rs = 0.f;
#pragma unroll
                for (int ni = 0; ni < 4; ++ni) {
                    int cc = col0 + wc * 64 + ni * 16 + l16;
                    float val = acc[mi][ni][i] * scale[cc] + offset[cc];
                    val = val > 0.f ? val : 0.1f * val;
                    rs += val * fuseW[cc];
                }
                rs += __shfl_xor(rs, 1, 64);
                rs += __shfl_xor(rs, 2, 64);
                rs += __shfl_xor(rs, 4, 64);
                rs += __shfl_xor(rs, 8, 64);
                if (l16 == 0) {
                    int r = row0 + wr * 64 + mi * 16 + q * 4 + i;
                    atomicAdd(facc + (size_t)blockIdx.z * faccStride + r, rs);
                }
            }
        return;
    }
#pragma unroll
    for (int mi = 0; mi < 4; ++mi)
#pragma unroll
        for (int ni = 0; ni < 4; ++ni)
#pragma unroll
            for (int i = 0; i < 4; ++i) {
                int r = row0 + wr * 64 + mi * 16 + q * 4 + i;
                int cc = col0 + wc * 64 + ni * 16 + l16;
                float val = acc[mi][ni][i];
                if (scale) val = val * scale[cc] + offset[cc];
                if (lrelu) val = val > 0.f ? val : 0.1f * val;
                Cp[(size_t)r * N + cc] = (bf16)val;
            }
}

extern "C" void kernel_launch(void* const* d_in, const int* in_sizes, int n_in,
                              void* d_out, int out_size, void* d_ws, size_t ws_size,
                              hipStream_t stream)
{
    const float* f_p   = (const float*)d_in[0];
    const float* f_g   = (const float*)d_in[1];
    const float* bn_g  = (const float*)d_in[2];
    const float* bn_b  = (const float*)d_in[3];
    const float* bn_m  = (const float*)d_in[4];
    const float* bn_v  = (const float*)d_in[5];
    const float* rf_W1 = (const float*)d_in[6];
    const float* rf_b1 = (const float*)d_in[7];
    const float* rf1_g = (const float*)d_in[8];
    const float* rf1_b = (const float*)d_in[9];
    const float* rf1_m = (const float*)d_in[10];
    const float* rf1_v = (const float*)d_in[11];
    const float* rf_W2 = (const float*)d_in[12];
    const float* rf_b2 = (const float*)d_in[13];
    const float* rf2_g = (const float*)d_in[14];
    const float* rf2_b = (const float*)d_in[15];
    const float* rf2_m = (const float*)d_in[16];
    const float* rf2_v = (const float*)d_in[17];
    const float* sfc_W = (const float*)d_in[18];
    const float* sfc_b = (const float*)d_in[19];
    const float* sbn_g = (const float*)d_in[20];
    const float* sbn_b = (const float*)d_in[21];
    const float* sbn_m = (const float*)d_in[22];
    const float* sbn_v = (const float*)d_in[23];
    const float* scl_W = (const float*)d_in[24];
    const float* scl_b = (const float*)d_in[25];
    const float* ffc_W = (const float*)d_in[26];
    const float* ffc_b = (const float*)d_in[27];
    const float* fbn_g = (const float*)d_in[28];
    const float* fbn_b = (const float*)d_in[29];
    const float* fbn_m = (const float*)d_in[30];
    const float* fbn_v = (const float*)d_in[31];
    const float* cls_W = (const float*)d_in[32];
    const float* cls_b = (const float*)d_in[33];

    const size_t MB = 1ull << 20;
    char* ws = (char*)d_ws;
    float* SC      = (float*)(ws);
    float *s0 = SC,        *o0 = SC + 1024;
    float *s1 = SC + 2048, *o1 = SC + 3072;
    float *s2 = SC + 4096, *o2 = SC + 5120;
    float *s3 = SC + 6144, *o3 = SC + 6656;
    float *s4 = SC + 7168, *o4 = SC + 7680;
    float* w_acc   = (float*)(ws + 65536);       // 256 KiB
    float* out_acc = (float*)(ws + 327680);      // 128 KiB
    bf16* wT       = (bf16*)(ws + 458752);       // 128 KiB
    bf16* W1T      = (bf16*)(ws + 1 * MB);
    bf16* W2T      = (bf16*)(ws + 3 * MB);
    bf16* sfcT     = (bf16*)(ws + 5 * MB);
    bf16* ffcT     = (bf16*)(ws + 6 * MB);

    int nc;
    if      (ws_size >= 170 * MB) nc = 1;        // confirmed since R3
    else if (ws_size >= 90 * MB)  nc = 2;
    else                          nc = 4;
    const int pc = 128 / nc;
    const int R  = pc * 256;
    const size_t hbytes = (size_t)R * 1024 * 2;
    bf16* bufA = (bf16*)(ws + 8 * MB);                    // h, then uT
    bf16* bufB = (bf16*)(ws + 8 * MB + hbytes);           // t
    bf16* bufC = (bf16*)(ws + 8 * MB + 2 * hbytes);       // u

    // 1. BN folds
    prep_kernel<<<dim3(4), 256, 0, stream>>>(bn_g, bn_b, bn_m, bn_v, nullptr, s0, o0, 1024);
    prep_kernel<<<dim3(4), 256, 0, stream>>>(rf1_g, rf1_b, rf1_m, rf1_v, rf_b1, s1, o1, 1024);
    prep_kernel<<<dim3(4), 256, 0, stream>>>(rf2_g, rf2_b, rf2_m, rf2_v, rf_b2, s2, o2, 1024);
    prep_kernel<<<dim3(2), 256, 0, stream>>>(sbn_g, sbn_b, sbn_m, sbn_v, sfc_b, s3, o3, 512);
    prep_kernel<<<dim3(2), 256, 0, stream>>>(fbn_g, fbn_b, fbn_m, fbn_v, ffc_b, s4, o4, 512);

    // 2. weight transposes (f32 -> bf16)
    wtrans_kernel<<<dim3(4, 1024), 256, 0, stream>>>(rf_W1, W1T, 1024, 1024);
    wtrans_kernel<<<dim3(4, 1024), 256, 0, stream>>>(rf_W2, W2T, 1024, 1024);
    wtrans_kernel<<<dim3(4, 512), 256, 0, stream>>>(sfc_W, sfcT, 1024, 512);
    wtrans_kernel<<<dim3(4, 512), 256, 0, stream>>>(ffc_W, ffcT, 1024, 512);

    // 3. zero accumulators (w_acc + out_acc contiguous)
    hipMemsetAsync(ws + 65536, 0, 393216, stream);

    // 4. affinity: w[g1][g2] = sum_h lrelu(sbn(dg@sfc_W))*scl_W[h] (pair-fused)
    gemm256<<<dim3(2, 256), 512, 0, stream>>>(
        nullptr, f_g, f_g, s0, o0, sfcT, nullptr, 1024, 512, 0,
        s3, o3, 1, scl_W, w_acc);
    // 5. wT[g2][g1] = bf16(w[g1][g2] + scl_b)
    wconv_kernel<<<dim3(256), 256, 0, stream>>>(w_acc, scl_b, wT);

    // 6. probe chunks
    for (int ci = 0; ci < nc; ++ci) {
        // h = lrelu(rf1(d @ W1 + b1))   [R,1024] (pair-fused)
        gemm256<<<dim3(4, R / 256), 512, 0, stream>>>(
            nullptr, f_p, f_g, s0, o0, W1T, bufA, 1024, 1024, ci * R,
            s1, o1, 1, nullptr, nullptr);
        // t = lrelu(rf2(h @ W2 + b2))   [R,1024]
        gemm256<<<dim3(4, R / 256), 512, 0, stream>>>(
            bufA, nullptr, nullptr, nullptr, nullptr, W2T, bufB, 1024, 1024, 0,
            s2, o2, 1, nullptr, nullptr);
        // u = t @ ffc_W                 [R,512]
        gemm256<<<dim3(2, R / 256), 512, 0, stream>>>(
            bufB, nullptr, nullptr, nullptr, nullptr, ffcT, bufC, 1024, 512, 0,
            nullptr, nullptr, 0, nullptr, nullptr);
        // uT[p][h][g] -> bufA (h dead)
        utrans_kernel<<<dim3(4, 8, pc), 256, 0, stream>>>(bufC, bufA);
        // fused feat+classifier -> out_acc
        gemm_kernel<<<dim3(4, 2, pc), 256, 0, stream>>>(
            wT, bufA, nullptr, 256, 512, (long long)512 * 256, 0,
            s4, o4, 1, cls_W, out_acc + (size_t)ci * pc * 256, 256);
    }
    // 7. d_out = out_acc + cls_b
    finout_kernel<<<dim3(128), 256, 0, stream>>>(out_acc, cls_b, (float*)d_out);
}